// Round 13
// baseline (3543.931 us; speedup 1.0000x reference)
//
#include <hip/hip_runtime.h>
#include <math.h>

#define BATCH 256
#define TT    784
#define HH    512
#define NCLS  10

#define NB 64          // batch groups
#define NJ 4           // blocks per group; block owns 128 cols
#define MB 4           // batch rows per group
#define HJ 128         // output cols per block
#define NT 512         // threads per block (8 waves)

typedef unsigned long long ull;
typedef unsigned int uint32;

#define AL(p)    __hip_atomic_load((p), __ATOMIC_RELAXED, __HIP_MEMORY_SCOPE_AGENT)
#define AS(p, v) __hip_atomic_store((p), (v), __ATOMIC_RELAXED, __HIP_MEMORY_SCOPE_AGENT)

// d_ws layout:
//   [0, 4096)   : wflags uint32[NB][16] — flag[bb][g*4+r] >= t  <=>  producer g's
//                 row r of h_t is visible (sc1-stored + producing wave's vmcnt drained).
//   [8192, ...) : double-buffered h state (2 * B * H f32, accessed sc1 relaxed).
//
// Single-barrier pipeline (vs R9's two): pbuf is double-buffered (parity t&1)
// and the reduction is done by the OWN-producer waves (g == jjg), which also
// consume the own-slice hp they write (intra-wave RAW, no barrier). After
// barrier B the six non-reducer waves immediately poll/stage step t+1, hiding
// the producer-side reduce+drain+flag latency. Proven construct set only
// (R8/R9): relaxed agent-scope atomics, s_waitcnt vmcnt(0), __syncthreads.

__global__ __launch_bounds__(256) void rnn_init_kernel(uint32* wflags) {
    const int i = blockIdx.x * blockDim.x + threadIdx.x;
    if (i < NB * 16) AS(&wflags[i], 0u);
}

__global__ __launch_bounds__(NT, 2) void rnn_main_kernel(
    const float* __restrict__ inputs, const int* __restrict__ order,
    const float* __restrict__ W_ih, const float* __restrict__ b_ih,
    const float* __restrict__ W_hh, const float* __restrict__ b_hh,
    float* __restrict__ hbuf, uint32* __restrict__ wflags)
{
    __shared__ float hp[MB * HH];            // 8 KB : h tile (canonical col layout)
    __shared__ float pbuf[2 * 16 * MB * HJ]; // 64 KB: partials, double-buffered by t&1
    __shared__ float xall[TT * MB];          // 12.5 KB
    __shared__ float wih_s[HJ];
    __shared__ float bias_s[HJ];

    const int tid   = threadIdx.x;
    const int blk   = blockIdx.x;
    const int bb    = blk & (NB - 1);
    const int jjg   = blk >> 6;              // producer id 0..3: cols [jjg*128, +128)
    const int jbase = jjg * HJ;
    const int bbase = bb * MB;
    const int j   = tid & 31;                // base col lane: cols {j,+32,+64,+96}
    const int kg  = tid >> 5;                // k-chunk 0..15 (32 k each)
    const int w   = tid >> 6;                // wave: k-window [64w,+64), producer g=w>>1
    const int g   = w >> 1;
    const int l   = tid & 63;
    const int r4  = l >> 4;                  // staging: batch row 0..3
    const int c4  = l & 15;                  // staging: 16 B chunk in 64-col window

    // ---- W_hh slice in NAMED registers: 4 cols x 32 k = 32 float4 (128 VGPR)
    const float4* wpa = (const float4*)(W_hh + (size_t)(jbase + j +  0) * HH + kg * 32);
    const float4* wpb = (const float4*)(W_hh + (size_t)(jbase + j + 32) * HH + kg * 32);
    const float4* wpc = (const float4*)(W_hh + (size_t)(jbase + j + 64) * HH + kg * 32);
    const float4* wpd = (const float4*)(W_hh + (size_t)(jbase + j + 96) * HH + kg * 32);
    const float4 wa0 = wpa[0], wa1 = wpa[1], wa2 = wpa[2], wa3 = wpa[3];
    const float4 wa4 = wpa[4], wa5 = wpa[5], wa6 = wpa[6], wa7 = wpa[7];
    const float4 wb0 = wpb[0], wb1 = wpb[1], wb2 = wpb[2], wb3 = wpb[3];
    const float4 wb4 = wpb[4], wb5 = wpb[5], wb6 = wpb[6], wb7 = wpb[7];
    const float4 wc0 = wpc[0], wc1 = wpc[1], wc2 = wpc[2], wc3 = wpc[3];
    const float4 wc4 = wpc[4], wc5 = wpc[5], wc6 = wpc[6], wc7 = wpc[7];
    const float4 wd0 = wpd[0], wd1 = wpd[1], wd2 = wpd[2], wd3 = wpd[3];
    const float4 wd4 = wpd[4], wd5 = wpd[5], wd6 = wpd[6], wd7 = wpd[7];

    if (tid < HJ) {
        wih_s[tid]  = W_ih[jbase + tid];
        bias_s[tid] = b_ih[jbase + tid] + b_hh[jbase + tid];
    }
    for (int idx = tid; idx < TT * MB; idx += NT) {
        const int t = idx >> 2;
        const int b = idx & (MB - 1);
        xall[idx] = inputs[(size_t)(bbase + b) * TT + order[t]];
    }
    ((float4*)hp)[tid] = make_float4(0.f, 0.f, 0.f, 0.f);   // h_0 = 0
    __syncthreads();

    const float4* hp4 = (const float4*)hp;

    for (int t = 0; t < TT; ++t) {
        const int p = t & 1;
        float4* P4 = (float4*)pbuf + (size_t)p * 2048;      // this step's partial buffer

        // ---- per-wave gate + stage: poll producer g's 4 row-flags, load 1 KB slice.
        //      Runs immediately after the previous step's barrier -> overlaps the
        //      remote producer's reduce/drain/flag latency.
        if (t > 0 && g != jjg) {
            const uint32 tg = (uint32)t;
            const ull* f8 = (const ull*)(wflags + bb * 16 + g * 4);
            for (;;) {
                const ull f0 = AL(f8), f1 = AL(f8 + 1);
                if ((uint32)f0 >= tg && (uint32)(f0 >> 32) >= tg &&
                    (uint32)f1 >= tg && (uint32)(f1 >> 32) >= tg) break;
            }
            const ull* src = (const ull*)(hbuf + (size_t)p * BATCH * HH
                                          + (size_t)(bbase + r4) * HH + w * 64 + c4 * 4);
            const ull u0 = AL(src), u1 = AL(src + 1);
            ull* hpu = (ull*)hp;
            const int di = (r4 * HH + w * 64 + c4 * 4) >> 1;
            hpu[di] = u0; hpu[di + 1] = u1;
        }
        // each wave's FMA reads ONLY its own hp window [64w, 64w+64) — written
        // either by this wave's staging (remote) or by this wave's reduce last
        // step (own-slice). Intra-wave RAW: compiler lgkmcnt. No barrier.

        // ---- partials: 4 rows x 4 cols, k-window 32
        float aa0=0.f,aa1=0.f,aa2=0.f,aa3=0.f;
        float ab0=0.f,ab1=0.f,ab2=0.f,ab3=0.f;
        float ac0=0.f,ac1=0.f,ac2=0.f,ac3=0.f;
        float ad0=0.f,ad1=0.f,ad2=0.f,ad3=0.f;

#define FMA4(ACC, WV, HV) \
        ACC = fmaf(WV.x, HV.x, ACC); ACC = fmaf(WV.y, HV.y, ACC); \
        ACC = fmaf(WV.z, HV.z, ACC); ACC = fmaf(WV.w, HV.w, ACC);
#define ROW(B) { \
        const float4* hr = hp4 + (B)*128 + kg*8; \
        const float4 h0=hr[0],h1=hr[1],h2=hr[2],h3=hr[3]; \
        const float4 h4=hr[4],h5=hr[5],h6=hr[6],h7=hr[7]; \
        FMA4(aa##B, wa0,h0) FMA4(aa##B, wa1,h1) FMA4(aa##B, wa2,h2) FMA4(aa##B, wa3,h3) \
        FMA4(aa##B, wa4,h4) FMA4(aa##B, wa5,h5) FMA4(aa##B, wa6,h6) FMA4(aa##B, wa7,h7) \
        FMA4(ab##B, wb0,h0) FMA4(ab##B, wb1,h1) FMA4(ab##B, wb2,h2) FMA4(ab##B, wb3,h3) \
        FMA4(ab##B, wb4,h4) FMA4(ab##B, wb5,h5) FMA4(ab##B, wb6,h6) FMA4(ab##B, wb7,h7) \
        FMA4(ac##B, wc0,h0) FMA4(ac##B, wc1,h1) FMA4(ac##B, wc2,h2) FMA4(ac##B, wc3,h3) \
        FMA4(ac##B, wc4,h4) FMA4(ac##B, wc5,h5) FMA4(ac##B, wc6,h6) FMA4(ac##B, wc7,h7) \
        FMA4(ad##B, wd0,h0) FMA4(ad##B, wd1,h1) FMA4(ad##B, wd2,h2) FMA4(ad##B, wd3,h3) \
        FMA4(ad##B, wd4,h4) FMA4(ad##B, wd5,h5) FMA4(ad##B, wd6,h6) FMA4(ad##B, wd7,h7) }

        ROW(0) ROW(1) ROW(2) ROW(3)
#undef ROW
#undef FMA4

        P4[(kg*4 + 0)*32 + j] = make_float4(aa0, ab0, ac0, ad0);
        P4[(kg*4 + 1)*32 + j] = make_float4(aa1, ab1, ac1, ad1);
        P4[(kg*4 + 2)*32 + j] = make_float4(aa2, ab2, ac2, ad2);
        P4[(kg*4 + 3)*32 + j] = make_float4(aa3, ab3, ac3, ad3);
        __syncthreads();                 // B: the ONE barrier — partials(t) ready

        // ---- reduce by the OWN-producer waves (g == jjg): 128 threads, rows 0..3
        if (g == jjg) {
            const int rr = (tid >> 5) & 3;   // row 0..3 (two rows per wave)
            float4 s = P4[rr * 32 + j];
            #pragma unroll
            for (int kk = 1; kk < 16; ++kk) {
                const float4 v = P4[(kk*4 + rr)*32 + j];
                s.x += v.x; s.y += v.y; s.z += v.z; s.w += v.w;
            }
            const float xv = xall[t * MB + rr];
            s.x = tanhf(s.x + xv * wih_s[j +  0] + bias_s[j +  0]);
            s.y = tanhf(s.y + xv * wih_s[j + 32] + bias_s[j + 32]);
            s.z = tanhf(s.z + xv * wih_s[j + 64] + bias_s[j + 64]);
            s.w = tanhf(s.w + xv * wih_s[j + 96] + bias_s[j + 96]);
            float* drow = hbuf + (size_t)(p ^ 1) * BATCH * HH
                               + (size_t)(bbase + rr) * HH + jbase;
            AS(&drow[j +  0], s.x);
            AS(&drow[j + 32], s.y);
            AS(&drow[j + 64], s.z);
            AS(&drow[j + 96], s.w);
            // own-slice: next step THIS wave reads these cols (intra-wave RAW)
            hp[rr * HH + jbase + j +  0] = s.x;
            hp[rr * HH + jbase + j + 32] = s.y;
            hp[rr * HH + jbase + j + 64] = s.z;
            hp[rr * HH + jbase + j + 96] = s.w;
            // drain THIS wave's sc1 stores (covers its 2 rows), publish row flags
            asm volatile("s_waitcnt vmcnt(0)" ::: "memory");
            if (j == 0) AS(&wflags[bb * 16 + jjg * 4 + rr], (uint32)(t + 1));
        }
        // no barrier C: pbuf parity covers WAR; own-slice is intra-wave;
        // non-reducer waves are already polling/staging step t+1.
    }
}

__global__ __launch_bounds__(256) void rnn_tail_kernel(
    const float* __restrict__ hfin,   // final h in buf 0 (TT even)
    const float* __restrict__ lin_W, const float* __restrict__ lin_b,
    const int* __restrict__ y, float* __restrict__ out)
{
    __shared__ float redf[256];
    __shared__ int   redi[256];
    const int b = threadIdx.x;
    const float* hrow = hfin + (size_t)b * HH;

    float logits[NCLS];
    #pragma unroll
    for (int c = 0; c < NCLS; ++c) {
        float s = lin_b[c];
        const float* wrow = lin_W + (size_t)c * HH;
        for (int k = 0; k < HH; k += 4) {
            float4 hv = *(const float4*)(hrow + k);
            float4 wv = *(const float4*)(wrow + k);
            s += hv.x * wv.x + hv.y * wv.y + hv.z * wv.z + hv.w * wv.w;
        }
        logits[c] = s;
    }
    int am = 0; float m = logits[0];
    #pragma unroll
    for (int c = 1; c < NCLS; ++c) if (logits[c] > m) { m = logits[c]; am = c; } // first-max
    float sum = 0.0f;
    #pragma unroll
    for (int c = 0; c < NCLS; ++c) sum += expf(logits[c] - m);
    const float lse = m + logf(sum);
    const int yy = y[b];
    redf[b] = lse - logits[yy];
    redi[b] = (am == yy) ? 1 : 0;
    __syncthreads();
    for (int s2 = 128; s2 > 0; s2 >>= 1) {
        if (b < s2) { redf[b] += redf[b + s2]; redi[b] += redi[b + s2]; }
        __syncthreads();
    }
    if (b == 0) {
        out[0] = redf[0] / (float)BATCH;  // loss
        out[1] = (float)redi[0];          // correct count
    }
}

extern "C" void kernel_launch(void* const* d_in, const int* in_sizes, int n_in,
                              void* d_out, int out_size, void* d_ws, size_t ws_size,
                              hipStream_t stream) {
    const float* inputs = (const float*)d_in[0];
    const int*   y      = (const int*)  d_in[1];
    const int*   order  = (const int*)  d_in[2];
    const float* W_ih   = (const float*)d_in[3];
    const float* b_ih   = (const float*)d_in[4];
    const float* W_hh   = (const float*)d_in[5];
    const float* b_hh   = (const float*)d_in[6];
    const float* lin_W  = (const float*)d_in[7];
    const float* lin_b  = (const float*)d_in[8];
    float* out = (float*)d_out;

    uint32* wflags = (uint32*)d_ws;
    float*  hbuf   = (float*)((char*)d_ws + 8192);

    hipLaunchKernelGGL(rnn_init_kernel, dim3(4), dim3(256), 0, stream, wflags);

    void* args[] = {(void*)&inputs, (void*)&order, (void*)&W_ih, (void*)&b_ih,
                    (void*)&W_hh, (void*)&b_hh, (void*)&hbuf, (void*)&wflags};
    hipError_t err = hipLaunchCooperativeKernel((void*)rnn_main_kernel,
                                                dim3(NB * NJ), dim3(NT), args, 0, stream);
    if (err != hipSuccess) {
        hipLaunchKernelGGL(rnn_main_kernel, dim3(NB * NJ), dim3(NT), 0, stream,
                           inputs, order, W_ih, b_ih, W_hh, b_hh, hbuf, wflags);
    }

    hipLaunchKernelGGL(rnn_tail_kernel, dim3(1), dim3(256), 0, stream,
                       hbuf, lin_W, lin_b, y, out);
}